// Round 9
// baseline (184.601 us; speedup 1.0000x reference)
//
#include <hip/hip_runtime.h>
#include <hip/hip_bf16.h>

#define Bn 4
#define Nn 2048
#define Fn 128
#define Hn 4
#define Dn 32
#define LOG2E 1.44269504f

typedef __attribute__((ext_vector_type(4))) float f32x4;
typedef __attribute__((ext_vector_type(4))) int   i32x4;
typedef __attribute__((ext_vector_type(8))) short s16x8;
typedef __attribute__((ext_vector_type(4))) short s16x4;
typedef _Float16 f16x8 __attribute__((ext_vector_type(8)));

typedef unsigned int uint;

__device__ __forceinline__ unsigned short f2h(float f) {
  _Float16 h = (_Float16)f;
  return __builtin_bit_cast(unsigned short, h);
}

// ---------------------------------------------------------------------------
// k_pack: adj (2048x2048 fp32 0/1) -> mh fp16 {0,1} mask (8 MB), row-major.
// W (H,F,D fp32) -> Wt[c][k] fp16 (c=h*32+d, pitch Fn) AND
// Waux[cc][k] fp16 (cc = h*2+{L,R}, rows 8..15 zero), Waux = (W@a)*log2e.
// ---------------------------------------------------------------------------
__global__ __launch_bounds__(256) void k_pack(
    const float* __restrict__ adj, const float* __restrict__ W,
    const float* __restrict__ aL, const float* __restrict__ aR,
    short* __restrict__ mh, short* __restrict__ Wt, short* __restrict__ Waux)
{
  const int blk = blockIdx.x;
  const int t = threadIdx.x;
  if (blk < Nn) {                       // adj row blk -> fp16 mask row
    const int i = t * 8;
    const float* ap = adj + (size_t)blk * Nn + i;
    const f32x4 a0 = *(const f32x4*)(ap);
    const f32x4 a1 = *(const f32x4*)(ap + 4);
    s16x8 m8;
    #pragma unroll
    for (int j = 0; j < 4; ++j) {
      m8[j]     = (a0[j] > 0.5f) ? (short)0x3C00 : (short)0;   // fp16 1.0 / 0.0
      m8[j + 4] = (a1[j] > 0.5f) ? (short)0x3C00 : (short)0;
    }
    *(s16x8*)(mh + (size_t)blk * Nn + i) = m8;
  } else if (t < 128) {                 // W pack, one block per head
    const int h = blk - Nn;
    const int f = t;
    const float* Wp = W + ((size_t)h * Fn + f) * Dn;   // W[h][f][0..31]
    float wv[32];
    float dl = 0.f, dr = 0.f;
    #pragma unroll
    for (int d4 = 0; d4 < 8; ++d4) {
      const f32x4 w4 = *(const f32x4*)(Wp + d4 * 4);
      #pragma unroll
      for (int j = 0; j < 4; ++j) {
        const int d = d4 * 4 + j;
        wv[d] = w4[j];
        dl = fmaf(w4[j], aL[h * Dn + d], dl);
        dr = fmaf(w4[j], aR[h * Dn + d], dr);
      }
    }
    #pragma unroll
    for (int d = 0; d < 32; ++d)
      Wt[(h * Dn + d) * Fn + f] = (short)f2h(wv[d]);
    Waux[(h * 2 + 0) * Fn + f] = (short)f2h(dl * LOG2E);
    Waux[(h * 2 + 1) * Fn + f] = (short)f2h(dr * LOG2E);
    if (h == 0) {
      #pragma unroll
      for (int cc = 8; cc < 16; ++cc) Waux[cc * Fn + f] = 0;
    }
  }
}

// ---------------------------------------------------------------------------
// k_proj: h = x@W via mfma_f32_16x16x32_f16, one wave / 16 rows; aux MFMA
// gives al/ar (log2-domain). Epilogue emits the SEPARABLE exp factors:
//   EA = 2^(al-2), FA = 2^(0.2*al-2)  -> packed u32 eafa[bh][n]
//   ER = 2^(ar-2), FR = 2^(0.2*ar-2)  -> fp16 arrays erh/frh[bh][n]
// so k_attn computes p = max(EA*ER, FA*FR)*mask with NO exp at all.
// ht = fp16 h stored transposed [bh][d][n].
// ---------------------------------------------------------------------------
__global__ __launch_bounds__(64, 4) void k_proj(
    const float* __restrict__ x, const short* __restrict__ Wt,
    const short* __restrict__ Waux,
    uint* __restrict__ eafa, short* __restrict__ erh, short* __restrict__ frh,
    short* __restrict__ ht)
{
  const int m0 = blockIdx.x * 16;          // flattened row base (B*N = 8192)
  const int b = m0 >> 11, nloc = m0 & 2047;
  const int lane = threadIdx.x;
  const int r = lane & 15, g = lane >> 4;

  const float* xp = x + (size_t)(m0 + r) * Fn + g * 8;
  f32x4 c[8] = {};
  f32x4 caux = {};
  #pragma unroll
  for (int ks = 0; ks < 4; ++ks) {
    const f32x4 xa = *(const f32x4*)(xp + ks * 32);
    const f32x4 xb = *(const f32x4*)(xp + ks * 32 + 4);
    f16x8 af;
    #pragma unroll
    for (int j = 0; j < 4; ++j) { af[j] = (_Float16)xa[j]; af[j + 4] = (_Float16)xb[j]; }
    const short* wp = Wt + r * Fn + ks * 32 + g * 8;     // col = cf*16 + r
    #pragma unroll
    for (int cf = 0; cf < 8; ++cf) {
      const f16x8 bf = __builtin_bit_cast(f16x8, *(const s16x8*)(wp + cf * 16 * Fn));
      c[cf] = __builtin_amdgcn_mfma_f32_16x16x32_f16(af, bf, c[cf], 0, 0, 0);
    }
    const f16x8 ba = __builtin_bit_cast(f16x8, *(const s16x8*)(Waux + r * Fn + ks * 32 + g * 8));
    caux = __builtin_amdgcn_mfma_f32_16x16x32_f16(af, ba, caux, 0, 0, 0);
  }

  // ht store: frag cf -> head cf>>1, d = (cf&1)*16 + r, rows nloc + g*4 + q
  #pragma unroll
  for (int cf = 0; cf < 8; ++cf) {
    const int hd = cf >> 1, d = (cf & 1) * 16 + r;
    s16x4 hv;
    #pragma unroll
    for (int q = 0; q < 4; ++q) hv[q] = (short)f2h(c[cf][q]);
    *(s16x4*)(ht + ((size_t)(b * Hn + hd) * Dn + d) * Nn + nloc + g * 4) = hv;
  }

  // caux[q] = aux[row = g*4+q][cc = r], cc = head*2 + {0=L,1=R}
  if (r < 8) {
    const int hh = r >> 1, side = r & 1;
    #pragma unroll
    for (int q = 0; q < 4; ++q) {
      const float v = caux[q];                         // al/ar * log2e
      const float Ev = __builtin_amdgcn_exp2f(v - 2.0f);
      const float Fv = __builtin_amdgcn_exp2f(fmaf(0.2f, v, -2.0f));
      const size_t idx = (size_t)(b * Hn + hh) * Nn + nloc + g * 4 + q;
      if (side == 0) {
        eafa[idx] = (uint)f2h(Ev) | ((uint)f2h(Fv) << 16);
      } else {
        erh[idx] = (short)f2h(Ev);
        frh[idx] = (short)f2h(Fv);
      }
    }
  }
}

// ---------------------------------------------------------------------------
// k_attn: fused masked softmax + PV. 8 waves/block on the same 16 m-rows,
// 8-way n-split (256 n/wave, 8 chunks of 32 n). Per chunk: 16 packed-f16 VALU
// (P = (ER*EA max FR*FA) * mask) + 3 MFMAs (PV-lo, PV-hi, ones row-sum).
// Explicit 2-stage depth-4 pipeline: 4 named slots x 5 streams (80 VGPR);
// asm keep-alives pin the prefetch (liveness only -- no sched_barrier walls,
// which caused the R7 regression). Two vmcnt drain points per wave total.
// ---------------------------------------------------------------------------
__global__ __launch_bounds__(512, 4) void k_attn(
    const uint* __restrict__ eafa,
    const short* __restrict__ erh, const short* __restrict__ frh,
    const short* __restrict__ mh, const short* __restrict__ ht,
    const float* __restrict__ bias, float* __restrict__ out)
{
  __shared__ float accS[8][16][33];
  __shared__ float lS[8][16];

  const int blk = blockIdx.x;              // 2048 = 16 bh * 128 m-tiles
  const int mt = blk & 127, bh = blk >> 7;
  const int b = bh >> 2, head = bh & 3;
  const int m0 = mt * 16;
  const int t = threadIdx.x;
  const int wv = t >> 6, lane = t & 63;
  const int r = lane & 15, g = lane >> 4;
  const int nb = wv * 256 + g * 64;        // this lane's 64-n range

  // broadcast factors for row m0+r
  const uint ef = eafa[(size_t)bh * Nn + m0 + r];
  uint ea2 = ef & 0xFFFFu;  ea2 |= ea2 << 16;
  uint fa2 = ef >> 16;      fa2 |= fa2 << 16;
  const i32x4 ea4 = {(int)ea2, (int)ea2, (int)ea2, (int)ea2};
  const i32x4 fa4 = {(int)fa2, (int)fa2, (int)fa2, (int)fa2};
  const f16x8 EA8 = __builtin_bit_cast(f16x8, ea4);
  const f16x8 FA8 = __builtin_bit_cast(f16x8, fa4);
  const f16x8 ones = {(_Float16)1.f, (_Float16)1.f, (_Float16)1.f, (_Float16)1.f,
                      (_Float16)1.f, (_Float16)1.f, (_Float16)1.f, (_Float16)1.f};

  const s16x8* erp = (const s16x8*)(erh + (size_t)bh * Nn + nb);
  const s16x8* frp = (const s16x8*)(frh + (size_t)bh * Nn + nb);
  const s16x8* mp  = (const s16x8*)(mh + (size_t)(m0 + r) * Nn + nb);
  const s16x8* hap = (const s16x8*)(ht + ((size_t)bh * Dn + r) * Nn + nb);
  const s16x8* hbp = (const s16x8*)(ht + ((size_t)bh * Dn + r + 16) * Nn + nb);

  f32x4 accA = {0.f,0.f,0.f,0.f}, accB = {0.f,0.f,0.f,0.f}, accL = {0.f,0.f,0.f,0.f};

  s16x8 S0e,S0f,S0m,S0a,S0b, S1e,S1f,S1m,S1a,S1b,
        S2e,S2f,S2m,S2a,S2b, S3e,S3f,S3m,S3a,S3b;

  #define LOAD(S, ci) \
    S##e = erp[ci]; S##f = frp[ci]; S##m = mp[ci]; S##a = hap[ci]; S##b = hbp[ci];
  #define KEEP(S) \
    asm volatile("" :: "v"(S##e), "v"(S##f), "v"(S##m), "v"(S##a), "v"(S##b));
  #define COMP(S) { \
    const f16x8 E = __builtin_bit_cast(f16x8, S##e) * EA8; \
    const f16x8 F = __builtin_bit_cast(f16x8, S##f) * FA8; \
    const f16x8 P = __builtin_elementwise_max(E, F) * __builtin_bit_cast(f16x8, S##m); \
    accA = __builtin_amdgcn_mfma_f32_16x16x32_f16(P, __builtin_bit_cast(f16x8, S##a), accA, 0, 0, 0); \
    accB = __builtin_amdgcn_mfma_f32_16x16x32_f16(P, __builtin_bit_cast(f16x8, S##b), accB, 0, 0, 0); \
    accL = __builtin_amdgcn_mfma_f32_16x16x32_f16(P, ones, accL, 0, 0, 0); }

  // stage 1: prefetch chunks 0-3, pin, compute while issuing 4-7 into freed slots
  LOAD(S0, 0) LOAD(S1, 1) LOAD(S2, 2) LOAD(S3, 3)
  KEEP(S0) KEEP(S1) KEEP(S2) KEEP(S3)
  COMP(S0) LOAD(S0, 4)
  COMP(S1) LOAD(S1, 5)
  COMP(S2) LOAD(S2, 6)
  COMP(S3) LOAD(S3, 7)
  // stage 2
  KEEP(S0) KEEP(S1) KEEP(S2) KEEP(S3)
  COMP(S0) COMP(S1) COMP(S2) COMP(S3)

  #undef LOAD
  #undef KEEP
  #undef COMP

  // merge 8 n-split partials. accL[q] = row-sum of P for row 4g+q.
  #pragma unroll
  for (int q = 0; q < 4; ++q) {
    accS[wv][4 * g + q][r]      = accA[q];
    accS[wv][4 * g + q][r + 16] = accB[q];
  }
  if (r == 0) {
    #pragma unroll
    for (int q = 0; q < 4; ++q) lS[wv][4 * g + q] = accL[q];
  }
  __syncthreads();

  // epilogue: 512 threads <-> 16 rows x 32 cols
  const int row = t >> 5, dc = t & 31;
  float L = 0.f, v = 0.f;
  #pragma unroll
  for (int w = 0; w < 8; ++w) { L += lS[w][row]; v += accS[w][row][dc]; }
  v = v / L + bias[head * Dn + dc];
  v = v > 0.f ? v : __expf(v) - 1.f;       // ELU(alpha=1)
  out[((size_t)b * Nn + m0 + row) * (Hn * Dn) + head * Dn + dc] = v;
}

extern "C" void kernel_launch(void* const* d_in, const int* in_sizes, int n_in,
                              void* d_out, int out_size, void* d_ws, size_t ws_size,
                              hipStream_t stream) {
  const float* x    = (const float*)d_in[0];
  const float* adj  = (const float*)d_in[1];
  const float* W    = (const float*)d_in[2];
  const float* aL   = (const float*)d_in[3];
  const float* aR   = (const float*)d_in[4];
  const float* bias = (const float*)d_in[5];
  float* out = (float*)d_out;

  // ws layout (~10.3 MB): eafa | erh | frh | ht | mh | Wt | Waux
  uint*  eafa = (uint*)d_ws;                                   // 128 KB
  short* erh  = (short*)(eafa + (Bn * Hn) * Nn);               // 64 KB
  short* frh  = erh + (Bn * Hn) * Nn;                          // 64 KB
  short* ht   = frh + (Bn * Hn) * Nn;                          // 2 MB
  short* mh   = ht + (size_t)(Bn * Hn) * Dn * Nn;              // 8 MB
  short* Wt   = mh + (size_t)Nn * Nn;                          // 32 KB
  short* Waux = Wt + (Hn * Dn) * Fn;                           // 4 KB

  hipLaunchKernelGGL(k_pack, dim3(Nn + Hn), dim3(256), 0, stream,
                     adj, W, aL, aR, mh, Wt, Waux);
  hipLaunchKernelGGL(k_proj, dim3((Bn * Nn) / 16), dim3(64), 0, stream,
                     x, Wt, Waux, eafa, erh, frh, ht);
  hipLaunchKernelGGL(k_attn, dim3((Bn * Hn) * (Nn / 16)), dim3(512), 0, stream,
                     eafa, erh, frh, mh, ht, bias, out);
}

// Round 11
// 128.765 us; speedup vs baseline: 1.4336x; 1.4336x over previous
//
#include <hip/hip_runtime.h>
#include <hip/hip_bf16.h>

#define Bn 4
#define Nn 2048
#define Fn 128
#define Hn 4
#define Dn 32
#define LOG2E 1.44269504f

typedef __attribute__((ext_vector_type(4))) float f32x4;
typedef __attribute__((ext_vector_type(4))) int   i32x4;
typedef __attribute__((ext_vector_type(8))) short s16x8;
typedef __attribute__((ext_vector_type(4))) short s16x4;
typedef _Float16 f16x8 __attribute__((ext_vector_type(8)));

typedef unsigned int uint;
typedef unsigned long long u64;

__device__ __forceinline__ unsigned short f2h(float f) {
  _Float16 h = (_Float16)f;
  return __builtin_bit_cast(unsigned short, h);
}

// ---------------------------------------------------------------------------
// k_pack: adj (2048x2048 fp32 0/1) -> bit mask (bit n&63 of u64 idx n>>6 per
// row; 256B/row). W (H,F,D fp32) -> Wt[c][k] fp16 (c=h*32+d, pitch Fn) AND
// Waux[cc][k] fp16 (cc=h*2+{L,R}, rows 8..15 zero), Waux=(W@a)*log2e.
// ---------------------------------------------------------------------------
__global__ __launch_bounds__(256) void k_pack(
    const float* __restrict__ adj, const float* __restrict__ W,
    const float* __restrict__ aL, const float* __restrict__ aR,
    u64* __restrict__ adjbits, short* __restrict__ Wt, short* __restrict__ Waux)
{
  const int blk = blockIdx.x;
  const int t = threadIdx.x;
  if (blk < Nn) {                       // adj row blk
    const int wv = t >> 6, lane = t & 63;
    const float* ap = adj + (size_t)blk * Nn;
    #pragma unroll
    for (int s = 0; s < 8; ++s) {
      const int n0 = (wv * 8 + s) * 64;
      const u64 m = __ballot(ap[n0 + lane] > 0.5f);
      if (lane == 0) adjbits[blk * 32 + wv * 8 + s] = m;
    }
  } else if (t < 128) {                 // W pack, one block per head
    const int h = blk - Nn;
    const int f = t;
    const float* Wp = W + ((size_t)h * Fn + f) * Dn;   // W[h][f][0..31]
    float wvv[32];
    float dl = 0.f, dr = 0.f;
    #pragma unroll
    for (int d4 = 0; d4 < 8; ++d4) {
      const f32x4 w4 = *(const f32x4*)(Wp + d4 * 4);
      #pragma unroll
      for (int j = 0; j < 4; ++j) {
        const int d = d4 * 4 + j;
        wvv[d] = w4[j];
        dl = fmaf(w4[j], aL[h * Dn + d], dl);
        dr = fmaf(w4[j], aR[h * Dn + d], dr);
      }
    }
    #pragma unroll
    for (int d = 0; d < 32; ++d)
      Wt[(h * Dn + d) * Fn + f] = (short)f2h(wvv[d]);
    Waux[(h * 2 + 0) * Fn + f] = (short)f2h(dl * LOG2E);
    Waux[(h * 2 + 1) * Fn + f] = (short)f2h(dr * LOG2E);
    if (h == 0) {
      #pragma unroll
      for (int cc = 8; cc < 16; ++cc) Waux[cc * Fn + f] = 0;
    }
  }
}

// ---------------------------------------------------------------------------
// k_proj: h = x@W via mfma_f32_16x16x32_f16, one wave / 16 rows; aux MFMA
// gives al/ar (log2-domain). Epilogue emits SEPARABLE exp factors:
//   EA=2^(al-2), FA=2^(0.2al-2) -> packed u32 eafa[bh][n]
//   ER=2^(ar-2), FR=2^(0.2ar-2) -> fp16 erh/frh[bh][n]
// ht = fp16 h stored transposed [bh][d][n].
// ---------------------------------------------------------------------------
__global__ __launch_bounds__(64, 4) void k_proj(
    const float* __restrict__ x, const short* __restrict__ Wt,
    const short* __restrict__ Waux,
    uint* __restrict__ eafa, short* __restrict__ erh, short* __restrict__ frh,
    short* __restrict__ ht)
{
  const int m0 = blockIdx.x * 16;          // flattened row base (B*N = 8192)
  const int b = m0 >> 11, nloc = m0 & 2047;
  const int lane = threadIdx.x;
  const int r = lane & 15, g = lane >> 4;

  const float* xp = x + (size_t)(m0 + r) * Fn + g * 8;
  f32x4 c[8] = {};
  f32x4 caux = {};
  #pragma unroll
  for (int ks = 0; ks < 4; ++ks) {
    const f32x4 xa = *(const f32x4*)(xp + ks * 32);
    const f32x4 xb = *(const f32x4*)(xp + ks * 32 + 4);
    f16x8 af;
    #pragma unroll
    for (int j = 0; j < 4; ++j) { af[j] = (_Float16)xa[j]; af[j + 4] = (_Float16)xb[j]; }
    const short* wp = Wt + r * Fn + ks * 32 + g * 8;     // col = cf*16 + r
    #pragma unroll
    for (int cf = 0; cf < 8; ++cf) {
      const f16x8 bf = __builtin_bit_cast(f16x8, *(const s16x8*)(wp + cf * 16 * Fn));
      c[cf] = __builtin_amdgcn_mfma_f32_16x16x32_f16(af, bf, c[cf], 0, 0, 0);
    }
    const f16x8 ba = __builtin_bit_cast(f16x8, *(const s16x8*)(Waux + r * Fn + ks * 32 + g * 8));
    caux = __builtin_amdgcn_mfma_f32_16x16x32_f16(af, ba, caux, 0, 0, 0);
  }

  // ht store: frag cf -> head cf>>1, d = (cf&1)*16 + r, rows nloc + g*4 + q
  #pragma unroll
  for (int cf = 0; cf < 8; ++cf) {
    const int hd = cf >> 1, d = (cf & 1) * 16 + r;
    s16x4 hv;
    #pragma unroll
    for (int q = 0; q < 4; ++q) hv[q] = (short)f2h(c[cf][q]);
    *(s16x4*)(ht + ((size_t)(b * Hn + hd) * Dn + d) * Nn + nloc + g * 4) = hv;
  }

  // caux[q] = aux[row = g*4+q][cc = r], cc = head*2 + {0=L,1=R}
  if (r < 8) {
    const int hh = r >> 1, side = r & 1;
    #pragma unroll
    for (int q = 0; q < 4; ++q) {
      const float v = caux[q];                         // al/ar * log2e
      const float Ev = __builtin_amdgcn_exp2f(v - 2.0f);
      const float Fv = __builtin_amdgcn_exp2f(fmaf(0.2f, v, -2.0f));
      const size_t idx = (size_t)(b * Hn + hh) * Nn + nloc + g * 4 + q;
      if (side == 0) {
        eafa[idx] = (uint)f2h(Ev) | ((uint)f2h(Fv) << 16);
      } else {
        erh[idx] = (short)f2h(Ev);
        frh[idx] = (short)f2h(Fv);
      }
    }
  }
}

// ---------------------------------------------------------------------------
// k_attn: GEMM-shaped. Each wave owns 16 m-rows x the FULL n=2048 sweep
// (64 chunks of 32 n) -> long steady-state loop the compiler can pipeline,
// waves fully independent (no merge, no accS, no trailing barrier).
// Block = 4 waves (64 rows), grid = 16 bh x 32 m-blocks = 512.
// er/fr staged once in LDS (16-lane broadcast reads); mask = bit-packed u64
// per 64 n (256 B/row, L1-resident across the sweep); P = max(ER*EA, FR*FA)
// in packed fp16, masked by sext pair-masks; 3 MFMAs (PV-lo, PV-hi, ones
// row-sum -> denominators land in the SAME lane as the outputs).
// ---------------------------------------------------------------------------
__global__ __launch_bounds__(256, 4) void k_attn(
    const u64* __restrict__ adjbits, const uint* __restrict__ eafa,
    const short* __restrict__ erh, const short* __restrict__ frh,
    const short* __restrict__ ht, const float* __restrict__ bias,
    float* __restrict__ out)
{
  __shared__ short er_s[Nn];               // 4 KB
  __shared__ short fr_s[Nn];               // 4 KB

  const int blk = blockIdx.x;              // 512 = 16 bh * 32 m-blocks
  const int bh = blk >> 5, mb = blk & 31;  // 32 consecutive blocks share bh (L2)
  const int b = bh >> 2, head = bh & 3;
  const int t = threadIdx.x;
  const int wv = t >> 6, lane = t & 63;
  const int r = lane & 15, g = lane >> 4;
  const int mwave = mb * 64 + wv * 16;     // wave's 16-row window

  // stage er/fr (fp16, 4 KB each): 256 threads x 16 B
  ((i32x4*)er_s)[t] = ((const i32x4*)(erh + (size_t)bh * Nn))[t];
  ((i32x4*)fr_s)[t] = ((const i32x4*)(frh + (size_t)bh * Nn))[t];

  // per-lane row broadcasts (A-row = r)
  const uint ef = eafa[(size_t)bh * Nn + mwave + r];
  uint ea2 = ef & 0xFFFFu;  ea2 |= ea2 << 16;
  uint fa2 = ef >> 16;      fa2 |= fa2 << 16;
  const i32x4 ea4 = {(int)ea2, (int)ea2, (int)ea2, (int)ea2};
  const i32x4 fa4 = {(int)fa2, (int)fa2, (int)fa2, (int)fa2};
  const f16x8 EA8 = __builtin_bit_cast(f16x8, ea4);
  const f16x8 FA8 = __builtin_bit_cast(f16x8, fa4);
  const f16x8 ones = {(_Float16)1.f, (_Float16)1.f, (_Float16)1.f, (_Float16)1.f,
                      (_Float16)1.f, (_Float16)1.f, (_Float16)1.f, (_Float16)1.f};

  const u64*   bitp = adjbits + (size_t)(mwave + r) * 32;
  const short* haP = ht + ((size_t)bh * Dn + r) * Nn;        // d = r
  const short* hbP = ht + ((size_t)bh * Dn + r + 16) * Nn;   // d = r + 16

  __syncthreads();                         // er_s/fr_s ready (only barrier)

  f32x4 accA = {0.f,0.f,0.f,0.f}, accB = {0.f,0.f,0.f,0.f}, accL = {0.f,0.f,0.f,0.f};

  // sext pair-mask: bits (2j,2j+1) of bb -> {lo16, hi16} all-ones/zeros
  #define PM(bb, j) (((uint)(((int)((bb) << (31 - 2*(j)))) >> 31) & 0xFFFFu) | \
                     ((uint)(((int)((bb) << (30 - 2*(j)))) >> 31) << 16))

  #pragma unroll 4
  for (int cu = 0; cu < 32; ++cu) {        // one u64 of mask bits = 2 chunks
    const u64 bits = bitp[cu];
    #pragma unroll
    for (int half = 0; half < 2; ++half) {
      const int nb0 = (cu * 2 + half) * 32 + g * 8;
      const s16x8 ha = *(const s16x8*)(haP + nb0);
      const s16x8 hb = *(const s16x8*)(hbP + nb0);
      const f16x8 er8 = __builtin_bit_cast(f16x8, *(const s16x8*)(er_s + nb0));
      const f16x8 fr8 = __builtin_bit_cast(f16x8, *(const s16x8*)(fr_s + nb0));
      const uint bb = (uint)(bits >> ((half * 4 + g) * 8)) & 0xffu;

      const f16x8 E = er8 * EA8;
      const f16x8 F = fr8 * FA8;
      f16x8 P = __builtin_elementwise_max(E, F);
      i32x4 pu = __builtin_bit_cast(i32x4, P);
      pu[0] &= (int)PM(bb, 0); pu[1] &= (int)PM(bb, 1);
      pu[2] &= (int)PM(bb, 2); pu[3] &= (int)PM(bb, 3);
      P = __builtin_bit_cast(f16x8, pu);

      accA = __builtin_amdgcn_mfma_f32_16x16x32_f16(P, __builtin_bit_cast(f16x8, ha), accA, 0, 0, 0);
      accB = __builtin_amdgcn_mfma_f32_16x16x32_f16(P, __builtin_bit_cast(f16x8, hb), accB, 0, 0, 0);
      accL = __builtin_amdgcn_mfma_f32_16x16x32_f16(P, ones, accL, 0, 0, 0);
    }
  }
  #undef PM

  // epilogue: lane-local. accA/accB[q] = out rows mwave+4g+q, cols r / r+16;
  // accL[q] = matching row-sum (denominator) in the SAME lane.
  const float bA = bias[head * Dn + r];
  const float bB = bias[head * Dn + r + 16];
  float* op = out + ((size_t)b * Nn + mwave) * (Hn * Dn) + head * Dn;
  #pragma unroll
  for (int q = 0; q < 4; ++q) {
    const float inv = 1.f / accL[q];
    float v0 = accA[q] * inv + bA;
    v0 = v0 > 0.f ? v0 : __expf(v0) - 1.f;         // ELU(alpha=1)
    op[(size_t)(4 * g + q) * (Hn * Dn) + r] = v0;
    float v1 = accB[q] * inv + bB;
    v1 = v1 > 0.f ? v1 : __expf(v1) - 1.f;
    op[(size_t)(4 * g + q) * (Hn * Dn) + r + 16] = v1;
  }
}

extern "C" void kernel_launch(void* const* d_in, const int* in_sizes, int n_in,
                              void* d_out, int out_size, void* d_ws, size_t ws_size,
                              hipStream_t stream) {
  const float* x    = (const float*)d_in[0];
  const float* adj  = (const float*)d_in[1];
  const float* W    = (const float*)d_in[2];
  const float* aL   = (const float*)d_in[3];
  const float* aR   = (const float*)d_in[4];
  const float* bias = (const float*)d_in[5];
  float* out = (float*)d_out;

  // ws layout (~2.8 MB): eafa | erh | frh | ht | adjbits | Wt | Waux
  uint*  eafa = (uint*)d_ws;                                   // 128 KB
  short* erh  = (short*)(eafa + (Bn * Hn) * Nn);               // 64 KB
  short* frh  = erh + (Bn * Hn) * Nn;                          // 64 KB
  short* ht   = frh + (Bn * Hn) * Nn;                          // 2 MB
  u64*   adjbits = (u64*)(ht + (size_t)(Bn * Hn) * Dn * Nn);   // 512 KB
  short* Wt   = (short*)(adjbits + Nn * (Nn / 64));            // 32 KB
  short* Waux = Wt + (Hn * Dn) * Fn;                           // 4 KB

  hipLaunchKernelGGL(k_pack, dim3(Nn + Hn), dim3(256), 0, stream,
                     adj, W, aL, aR, adjbits, Wt, Waux);
  hipLaunchKernelGGL(k_proj, dim3((Bn * Nn) / 16), dim3(64), 0, stream,
                     x, Wt, Waux, eafa, erh, frh, ht);
  hipLaunchKernelGGL(k_attn, dim3(16 * 32), dim3(256), 0, stream,
                     adjbits, eafa, erh, frh, ht, bias, out);
}

// Round 12
// 118.962 us; speedup vs baseline: 1.5518x; 1.0824x over previous
//
#include <hip/hip_runtime.h>
#include <hip/hip_bf16.h>

#define Bn 4
#define Nn 2048
#define Fn 128
#define Hn 4
#define Dn 32
#define LOG2E 1.44269504f

typedef __attribute__((ext_vector_type(4))) float f32x4;
typedef __attribute__((ext_vector_type(4))) int   i32x4;
typedef __attribute__((ext_vector_type(8))) short s16x8;
typedef __attribute__((ext_vector_type(4))) short s16x4;
typedef _Float16 f16x8 __attribute__((ext_vector_type(8)));

typedef unsigned int uint;
typedef unsigned long long u64;

__device__ __forceinline__ unsigned short f2h(float f) {
  _Float16 h = (_Float16)f;
  return __builtin_bit_cast(unsigned short, h);
}

// ---------------------------------------------------------------------------
// k_pack: adj (2048x2048 fp32 0/1) -> bit mask (bit n&63 of u64 idx n>>6 per
// row; 256B/row). W (H,F,D fp32) -> Wt[c][k] fp16 (c=h*32+d, pitch Fn) AND
// Waux[cc][k] fp16 (cc=h*2+{L,R}, rows 8..15 zero), Waux=(W@a)*log2e.
// ---------------------------------------------------------------------------
__global__ __launch_bounds__(256) void k_pack(
    const float* __restrict__ adj, const float* __restrict__ W,
    const float* __restrict__ aL, const float* __restrict__ aR,
    u64* __restrict__ adjbits, short* __restrict__ Wt, short* __restrict__ Waux)
{
  const int blk = blockIdx.x;
  const int t = threadIdx.x;
  if (blk < Nn) {                       // adj row blk
    const int wv = t >> 6, lane = t & 63;
    const float* ap = adj + (size_t)blk * Nn;
    #pragma unroll
    for (int s = 0; s < 8; ++s) {
      const int n0 = (wv * 8 + s) * 64;
      const u64 m = __ballot(ap[n0 + lane] > 0.5f);
      if (lane == 0) adjbits[blk * 32 + wv * 8 + s] = m;
    }
  } else if (t < 128) {                 // W pack, one block per head
    const int h = blk - Nn;
    const int f = t;
    const float* Wp = W + ((size_t)h * Fn + f) * Dn;   // W[h][f][0..31]
    float wvv[32];
    float dl = 0.f, dr = 0.f;
    #pragma unroll
    for (int d4 = 0; d4 < 8; ++d4) {
      const f32x4 w4 = *(const f32x4*)(Wp + d4 * 4);
      #pragma unroll
      for (int j = 0; j < 4; ++j) {
        const int d = d4 * 4 + j;
        wvv[d] = w4[j];
        dl = fmaf(w4[j], aL[h * Dn + d], dl);
        dr = fmaf(w4[j], aR[h * Dn + d], dr);
      }
    }
    #pragma unroll
    for (int d = 0; d < 32; ++d)
      Wt[(h * Dn + d) * Fn + f] = (short)f2h(wvv[d]);
    Waux[(h * 2 + 0) * Fn + f] = (short)f2h(dl * LOG2E);
    Waux[(h * 2 + 1) * Fn + f] = (short)f2h(dr * LOG2E);
    if (h == 0) {
      #pragma unroll
      for (int cc = 8; cc < 16; ++cc) Waux[cc * Fn + f] = 0;
    }
  }
}

// ---------------------------------------------------------------------------
// k_proj: h = x@W via mfma_f32_16x16x32_f16, one wave / 16 rows; aux MFMA
// gives al/ar (log2-domain). Epilogue emits SEPARABLE exp factors:
//   EA=2^(al-2), FA=2^(0.2al-2) -> packed u32 eafa[bh][n]
//   ER=2^(ar-2), FR=2^(0.2ar-2) -> fp16 erh/frh[bh][n]
// ht = fp16 h stored transposed [bh][d][n].
// ---------------------------------------------------------------------------
__global__ __launch_bounds__(64, 4) void k_proj(
    const float* __restrict__ x, const short* __restrict__ Wt,
    const short* __restrict__ Waux,
    uint* __restrict__ eafa, short* __restrict__ erh, short* __restrict__ frh,
    short* __restrict__ ht)
{
  const int m0 = blockIdx.x * 16;          // flattened row base (B*N = 8192)
  const int b = m0 >> 11, nloc = m0 & 2047;
  const int lane = threadIdx.x;
  const int r = lane & 15, g = lane >> 4;

  const float* xp = x + (size_t)(m0 + r) * Fn + g * 8;
  f32x4 c[8] = {};
  f32x4 caux = {};
  #pragma unroll
  for (int ks = 0; ks < 4; ++ks) {
    const f32x4 xa = *(const f32x4*)(xp + ks * 32);
    const f32x4 xb = *(const f32x4*)(xp + ks * 32 + 4);
    f16x8 af;
    #pragma unroll
    for (int j = 0; j < 4; ++j) { af[j] = (_Float16)xa[j]; af[j + 4] = (_Float16)xb[j]; }
    const short* wp = Wt + r * Fn + ks * 32 + g * 8;     // col = cf*16 + r
    #pragma unroll
    for (int cf = 0; cf < 8; ++cf) {
      const f16x8 bf = __builtin_bit_cast(f16x8, *(const s16x8*)(wp + cf * 16 * Fn));
      c[cf] = __builtin_amdgcn_mfma_f32_16x16x32_f16(af, bf, c[cf], 0, 0, 0);
    }
    const f16x8 ba = __builtin_bit_cast(f16x8, *(const s16x8*)(Waux + r * Fn + ks * 32 + g * 8));
    caux = __builtin_amdgcn_mfma_f32_16x16x32_f16(af, ba, caux, 0, 0, 0);
  }

  // ht store: frag cf -> head cf>>1, d = (cf&1)*16 + r, rows nloc + g*4 + q
  #pragma unroll
  for (int cf = 0; cf < 8; ++cf) {
    const int hd = cf >> 1, d = (cf & 1) * 16 + r;
    s16x4 hv;
    #pragma unroll
    for (int q = 0; q < 4; ++q) hv[q] = (short)f2h(c[cf][q]);
    *(s16x4*)(ht + ((size_t)(b * Hn + hd) * Dn + d) * Nn + nloc + g * 4) = hv;
  }

  // caux[q] = aux[row = g*4+q][cc = r], cc = head*2 + {0=L,1=R}
  if (r < 8) {
    const int hh = r >> 1, side = r & 1;
    #pragma unroll
    for (int q = 0; q < 4; ++q) {
      const float v = caux[q];                         // al/ar * log2e
      const float Ev = __builtin_amdgcn_exp2f(v - 2.0f);
      const float Fv = __builtin_amdgcn_exp2f(fmaf(0.2f, v, -2.0f));
      const size_t idx = (size_t)(b * Hn + hh) * Nn + nloc + g * 4 + q;
      if (side == 0) {
        eafa[idx] = (uint)f2h(Ev) | ((uint)f2h(Fv) << 16);
      } else {
        erh[idx] = (short)f2h(Ev);
        frh[idx] = (short)f2h(Fv);
      }
    }
  }
}

// ---------------------------------------------------------------------------
// k_attn: GEMM-shaped, full n-sweep per wave (64 chunks of 32 n), waves
// independent (no merge, no trailing barrier). Grid supplies only 2 waves/EU,
// so amdgpu_waves_per_eu(1,2) tells the allocator to STOP minimizing VGPRs
// for occupancy we can't use (R11: VGPR=28 -> serial load-wait-use) and lets
// the scheduler hoist the unroll-4 load groups (16 dwordx4 in flight).
// Dual accumulator sets (even/odd half) relax the MFMA dependence chain.
// ---------------------------------------------------------------------------
__global__ __launch_bounds__(256)
__attribute__((amdgpu_waves_per_eu(1, 2)))
void k_attn(
    const u64* __restrict__ adjbits, const uint* __restrict__ eafa,
    const short* __restrict__ erh, const short* __restrict__ frh,
    const short* __restrict__ ht, const float* __restrict__ bias,
    float* __restrict__ out)
{
  __shared__ short er_s[Nn];               // 4 KB
  __shared__ short fr_s[Nn];               // 4 KB

  const int blk = blockIdx.x;              // 512 = 16 bh * 32 m-blocks
  const int bh = blk >> 5, mb = blk & 31;  // 32 consecutive blocks share bh (L2)
  const int b = bh >> 2, head = bh & 3;
  const int t = threadIdx.x;
  const int wv = t >> 6, lane = t & 63;
  const int r = lane & 15, g = lane >> 4;
  const int mwave = mb * 64 + wv * 16;     // wave's 16-row window

  // stage er/fr (fp16, 4 KB each): 256 threads x 16 B
  ((i32x4*)er_s)[t] = ((const i32x4*)(erh + (size_t)bh * Nn))[t];
  ((i32x4*)fr_s)[t] = ((const i32x4*)(frh + (size_t)bh * Nn))[t];

  // per-lane row broadcasts (A-row = r)
  const uint ef = eafa[(size_t)bh * Nn + mwave + r];
  uint ea2 = ef & 0xFFFFu;  ea2 |= ea2 << 16;
  uint fa2 = ef >> 16;      fa2 |= fa2 << 16;
  const i32x4 ea4 = {(int)ea2, (int)ea2, (int)ea2, (int)ea2};
  const i32x4 fa4 = {(int)fa2, (int)fa2, (int)fa2, (int)fa2};
  const f16x8 EA8 = __builtin_bit_cast(f16x8, ea4);
  const f16x8 FA8 = __builtin_bit_cast(f16x8, fa4);
  const f16x8 ones = {(_Float16)1.f, (_Float16)1.f, (_Float16)1.f, (_Float16)1.f,
                      (_Float16)1.f, (_Float16)1.f, (_Float16)1.f, (_Float16)1.f};

  const u64*   bitp = adjbits + (size_t)(mwave + r) * 32;
  const short* haP = ht + ((size_t)bh * Dn + r) * Nn;        // d = r
  const short* hbP = ht + ((size_t)bh * Dn + r + 16) * Nn;   // d = r + 16

  __syncthreads();                         // er_s/fr_s ready (only barrier)

  f32x4 accA0 = {0.f,0.f,0.f,0.f}, accB0 = {0.f,0.f,0.f,0.f}, accL0 = {0.f,0.f,0.f,0.f};
  f32x4 accA1 = {0.f,0.f,0.f,0.f}, accB1 = {0.f,0.f,0.f,0.f}, accL1 = {0.f,0.f,0.f,0.f};

  // sext pair-mask: bits (2j,2j+1) of bb -> {lo16, hi16} all-ones/zeros
  #define PM(bb, j) (((uint)(((int)((bb) << (31 - 2*(j)))) >> 31) & 0xFFFFu) | \
                     ((uint)(((int)((bb) << (30 - 2*(j)))) >> 31) << 16))

  #pragma unroll 4
  for (int cu = 0; cu < 32; ++cu) {        // one u64 of mask bits = 2 halves
    // ---- load group (independent; scheduler hoists across the body) ----
    const u64 bits = bitp[cu];
    const int n0 = cu * 64 + g * 8;
    const s16x8 ha0 = *(const s16x8*)(haP + n0);
    const s16x8 hb0 = *(const s16x8*)(hbP + n0);
    const s16x8 ha1 = *(const s16x8*)(haP + n0 + 32);
    const s16x8 hb1 = *(const s16x8*)(hbP + n0 + 32);
    const f16x8 er80 = __builtin_bit_cast(f16x8, *(const s16x8*)(er_s + n0));
    const f16x8 fr80 = __builtin_bit_cast(f16x8, *(const s16x8*)(fr_s + n0));
    const f16x8 er81 = __builtin_bit_cast(f16x8, *(const s16x8*)(er_s + n0 + 32));
    const f16x8 fr81 = __builtin_bit_cast(f16x8, *(const s16x8*)(fr_s + n0 + 32));
    const uint bb0 = (uint)(bits >> (g * 8)) & 0xffu;
    const uint bb1 = (uint)(bits >> ((4 + g) * 8)) & 0xffu;

    // ---- compute half 0 -> acc set 0 ----
    {
      f16x8 P = __builtin_elementwise_max(er80 * EA8, fr80 * FA8);
      i32x4 pu = __builtin_bit_cast(i32x4, P);
      pu[0] &= (int)PM(bb0, 0); pu[1] &= (int)PM(bb0, 1);
      pu[2] &= (int)PM(bb0, 2); pu[3] &= (int)PM(bb0, 3);
      P = __builtin_bit_cast(f16x8, pu);
      accA0 = __builtin_amdgcn_mfma_f32_16x16x32_f16(P, __builtin_bit_cast(f16x8, ha0), accA0, 0, 0, 0);
      accB0 = __builtin_amdgcn_mfma_f32_16x16x32_f16(P, __builtin_bit_cast(f16x8, hb0), accB0, 0, 0, 0);
      accL0 = __builtin_amdgcn_mfma_f32_16x16x32_f16(P, ones, accL0, 0, 0, 0);
    }
    // ---- compute half 1 -> acc set 1 ----
    {
      f16x8 P = __builtin_elementwise_max(er81 * EA8, fr81 * FA8);
      i32x4 pu = __builtin_bit_cast(i32x4, P);
      pu[0] &= (int)PM(bb1, 0); pu[1] &= (int)PM(bb1, 1);
      pu[2] &= (int)PM(bb1, 2); pu[3] &= (int)PM(bb1, 3);
      P = __builtin_bit_cast(f16x8, pu);
      accA1 = __builtin_amdgcn_mfma_f32_16x16x32_f16(P, __builtin_bit_cast(f16x8, ha1), accA1, 0, 0, 0);
      accB1 = __builtin_amdgcn_mfma_f32_16x16x32_f16(P, __builtin_bit_cast(f16x8, hb1), accB1, 0, 0, 0);
      accL1 = __builtin_amdgcn_mfma_f32_16x16x32_f16(P, ones, accL1, 0, 0, 0);
    }
  }
  #undef PM

  const f32x4 accA = accA0 + accA1;
  const f32x4 accB = accB0 + accB1;
  const f32x4 accL = accL0 + accL1;

  // epilogue: lane-local. accA/accB[q] = out rows mwave+4g+q, cols r / r+16;
  // accL[q] = matching row-sum (denominator) in the SAME lane.
  const float bA = bias[head * Dn + r];
  const float bB = bias[head * Dn + r + 16];
  float* op = out + ((size_t)b * Nn + mwave) * (Hn * Dn) + head * Dn;
  #pragma unroll
  for (int q = 0; q < 4; ++q) {
    const float inv = 1.f / accL[q];
    float v0 = accA[q] * inv + bA;
    v0 = v0 > 0.f ? v0 : __expf(v0) - 1.f;         // ELU(alpha=1)
    op[(size_t)(4 * g + q) * (Hn * Dn) + r] = v0;
    float v1 = accB[q] * inv + bB;
    v1 = v1 > 0.f ? v1 : __expf(v1) - 1.f;
    op[(size_t)(4 * g + q) * (Hn * Dn) + r + 16] = v1;
  }
}

extern "C" void kernel_launch(void* const* d_in, const int* in_sizes, int n_in,
                              void* d_out, int out_size, void* d_ws, size_t ws_size,
                              hipStream_t stream) {
  const float* x    = (const float*)d_in[0];
  const float* adj  = (const float*)d_in[1];
  const float* W    = (const float*)d_in[2];
  const float* aL   = (const float*)d_in[3];
  const float* aR   = (const float*)d_in[4];
  const float* bias = (const float*)d_in[5];
  float* out = (float*)d_out;

  // ws layout (~2.8 MB): eafa | erh | frh | ht | adjbits | Wt | Waux
  uint*  eafa = (uint*)d_ws;                                   // 128 KB
  short* erh  = (short*)(eafa + (Bn * Hn) * Nn);               // 64 KB
  short* frh  = erh + (Bn * Hn) * Nn;                          // 64 KB
  short* ht   = frh + (Bn * Hn) * Nn;                          // 2 MB
  u64*   adjbits = (u64*)(ht + (size_t)(Bn * Hn) * Dn * Nn);   // 512 KB
  short* Wt   = (short*)(adjbits + Nn * (Nn / 64));            // 32 KB
  short* Waux = Wt + (Hn * Dn) * Fn;                           // 4 KB

  hipLaunchKernelGGL(k_pack, dim3(Nn + Hn), dim3(256), 0, stream,
                     adj, W, aL, aR, adjbits, Wt, Waux);
  hipLaunchKernelGGL(k_proj, dim3((Bn * Nn) / 16), dim3(64), 0, stream,
                     x, Wt, Waux, eafa, erh, frh, ht);
  hipLaunchKernelGGL(k_attn, dim3(16 * 32), dim3(256), 0, stream,
                     adjbits, eafa, erh, frh, ht, bias, out);
}